// Round 13
// baseline (401.697 us; speedup 1.0000x reference)
//
#include <hip/hip_runtime.h>
#include <hip/hip_bf16.h>
#include <math.h>

#define NN 50000
#define EE 500000
#define DIN 384
#define HIDD 128
#define NHEAD 8
#define OUTD 16

typedef __attribute__((ext_vector_type(8))) __bf16 bf16x8;
typedef __attribute__((ext_vector_type(4))) float f32x4;

__device__ __forceinline__ ushort f2bf(float f) {
  union { float f; unsigned u; } v; v.f = f;
  unsigned r = v.u + 0x7fffu + ((v.u >> 16) & 1u);
  return (ushort)(r >> 16);
}
__device__ __forceinline__ float bflo(unsigned w) {
  union { unsigned u; float f; } v; v.u = w << 16; return v.f;
}
__device__ __forceinline__ float bfhi(unsigned w) {
  union { unsigned u; float f; } v; v.u = w & 0xffff0000u; return v.f;
}

#define SCAN_BS 256
#define SCAN_NBLK ((NN + SCAN_BS - 1) / SCAN_BS)  // 196

// ---------------- init: zero counts + scan-aggregate sentinels ----------------
__global__ void init_kernel(int* __restrict__ counts, int* __restrict__ agg, int n) {
  int i = blockIdx.x * blockDim.x + threadIdx.x;
  if (i < n) counts[i] = 0;
  if (i < SCAN_NBLK) agg[i] = -1;   // lookback sentinel (aggregates are >= 0)
}

// ---------------- fused prep_weights + hist (independent; block partition) -------
#define HBLK ((EE + 255) / 256)      // 1954
#define PBLK ((107520 + 255) / 256)  // 420
__global__ void prep_hist(const float* __restrict__ proj_w,
                          const float* __restrict__ lin_w,
                          const float* __restrict__ cls_w1,
                          const float* __restrict__ cls_w2,
                          ushort* __restrict__ wt,
                          const int* __restrict__ dst,
                          int* __restrict__ counts) {
  const int bx = blockIdx.x;
  if (bx < HBLK) {
    int i = bx * 256 + threadIdx.x;
    if (i < EE) atomicAdd(&counts[dst[i]], 1);
    return;
  }
  int i = (bx - HBLK) * 256 + threadIdx.x;
  if (i < 49152) {
    int k = i >> 7, n = i & 127;
    wt[n * 384 + k] = f2bf(proj_w[i]);
  } else if (i < 98304) {
    int j = i - 49152;
    int l = j >> 14, rem = j & 16383;
    int k = rem >> 7, n = rem & 127;
    wt[49152 + l * 16384 + n * 128 + k] = f2bf(lin_w[j]);
  } else if (i < 106496) {
    int j = i - 98304;
    int n = j >> 7, k = j & 127;
    wt[98304 + n * 128 + k] = f2bf(cls_w1[k * 64 + n]);
  } else if (i < 107520) {
    int j = i - 106496;
    int n = j >> 6, k = j & 63;
    wt[106496 + n * 64 + k] = f2bf(cls_w2[k * 16 + n]);
  }
}

// ---------------- single-dispatch decoupled-lookback scan ----------------------
// 196 blocks (all co-resident on 256 CUs -> spin is deadlock-free). Device-scope
// atomics give cross-XCD visibility (G12/G16).
__global__ __launch_bounds__(256) void scan_lookback(const int* __restrict__ counts,
                                                     int* __restrict__ agg,
                                                     int* __restrict__ rowptr,
                                                     int* __restrict__ woff, int n) {
  __shared__ int buf[256];
  __shared__ int red[256];
  const int b = blockIdx.x, t = threadIdx.x;
  const int i = b * 256 + t;
  int v = (i < n) ? counts[i] : 0;
  buf[t] = v;
  __syncthreads();
  #pragma unroll
  for (int off = 1; off < 256; off <<= 1) {
    int u = (t >= off) ? buf[t - off] : 0;
    __syncthreads();
    buf[t] += u;
    __syncthreads();
  }
  int incl = buf[t];
  if (t == 0) atomicExch(&agg[b], buf[255]);   // publish tile aggregate
  int mine = 0;
  if (t < b) {
    int a;
    do { a = atomicAdd(&agg[t], 0); } while (a < 0);
    mine = a;
  }
  red[t] = mine;
  __syncthreads();
  #pragma unroll
  for (int off = 128; off; off >>= 1) {
    if (t < off) red[t] += red[t + off];
    __syncthreads();
  }
  int excl = red[0] + incl - v;
  if (i < n) { rowptr[i] = excl; woff[i] = excl; }
  if (i == n - 1) rowptr[n] = excl + v;
}

#define LDS_STRIDE 68
#define SBLK ((EE + 255) / 256)   // 1954 scatter blocks
#define GBLK ((NN + 31) / 32)     // 1563 GEMM blocks

// ---------------- fused scatter + proj GEMM (R10 mapping: verified best) ---------
// Blocks [0, SBLK): CSR scatter (short, returns before any barrier). Blocks
// [SBLK, SBLK+GBLK): proj GEMM. R12's interleaved mapping REGRESSED (GEMM locality
// loss > overlap gain); scatter-first is the verified-best layout (R10: 366.3us).
__global__ __launch_bounds__(256) void scatter_proj(
    const int* __restrict__ src, const int* __restrict__ dst,
    int* __restrict__ woff, int* __restrict__ col,
    const float* __restrict__ A, const ushort* __restrict__ Bt,
    const float* __restrict__ bias, ushort* __restrict__ C, int M) {
  __shared__ ushort sA[32 * LDS_STRIDE];
  __shared__ ushort sB[128 * LDS_STRIDE];
  const int bx = blockIdx.x;
  if (bx < SBLK) {
    int i = bx * 256 + threadIdx.x;
    if (i < EE) {
      int p = atomicAdd(&woff[dst[i]], 1);
      col[p] = src[i];
    }
    return;
  }
  const int tid = threadIdx.x;
  const int w = tid >> 6, lane = tid & 63;
  const int q = lane >> 4, lm = lane & 15;
  const int m0 = (bx - SBLK) * 32;

  f32x4 acc[2][2];
  #pragma unroll
  for (int i = 0; i < 2; i++)
    #pragma unroll
    for (int j = 0; j < 2; j++) acc[i][j] = {0.f, 0.f, 0.f, 0.f};

  for (int k0 = 0; k0 < DIN; k0 += 64) {
    __syncthreads();
    #pragma unroll
    for (int p = 0; p < 2; ++p) {
      int idx = p * 256 + tid;
      int r = idx >> 4;
      int c = (idx & 15) << 2;
      int row = min(m0 + r, M - 1);
      float4 v = *(const float4*)(A + (size_t)row * DIN + k0 + c);
      ushort4 u;
      u.x = f2bf(v.x); u.y = f2bf(v.y); u.z = f2bf(v.z); u.w = f2bf(v.w);
      *(ushort4*)&sA[r * LDS_STRIDE + c] = u;
    }
    #pragma unroll
    for (int p = 0; p < 4; ++p) {
      int idx = p * 256 + tid;
      int r = idx >> 3;
      int c = (idx & 7) << 3;
      *(bf16x8*)&sB[r * LDS_STRIDE + c] = *(const bf16x8*)(Bt + (size_t)r * DIN + k0 + c);
    }
    __syncthreads();
    #pragma unroll
    for (int ks = 0; ks < 2; ++ks) {
      bf16x8 af[2], bfv[2];
      #pragma unroll
      for (int i = 0; i < 2; ++i)
        af[i] = *(const bf16x8*)&sA[(i * 16 + lm) * LDS_STRIDE + ks * 32 + q * 8];
      #pragma unroll
      for (int j = 0; j < 2; ++j)
        bfv[j] = *(const bf16x8*)&sB[(w * 32 + j * 16 + lm) * LDS_STRIDE + ks * 32 + q * 8];
      #pragma unroll
      for (int i = 0; i < 2; ++i)
        #pragma unroll
        for (int j = 0; j < 2; ++j)
          acc[i][j] = __builtin_amdgcn_mfma_f32_16x16x32_bf16(af[i], bfv[j], acc[i][j], 0, 0, 0);
    }
  }
  #pragma unroll
  for (int i = 0; i < 2; ++i) {
    #pragma unroll
    for (int r = 0; r < 4; ++r) {
      int row = m0 + i * 16 + q * 4 + r;
      if (row < M) {
        #pragma unroll
        for (int j = 0; j < 2; ++j) {
          int colc = w * 32 + j * 16 + lm;
          float v = acc[i][j][r] + bias[colc];
          C[(size_t)row * 128 + colc] = f2bf(fmaxf(v, 0.f));
        }
      }
    }
  }
}

// ---------------- MFMA GEMM: C[M,128] = A[M,128] @ B[128,128], bf16 out ----------
// 32-row M-tile (1563 blocks, 7 blocks/CU at 21.75 KB LDS — R5/R6 verified TLP win).
// ATT: fused attention logits; head = wave*2 + j, chan = lm (16-lane shfl reduce).
template<typename AT, int KK, bool RELU_BIAS, bool ATT>
__global__ __launch_bounds__(256) void mfma_gemm32(const AT* __restrict__ A,
                                                   const ushort* __restrict__ Bt,
                                                   const float* __restrict__ bias,
                                                   ushort* __restrict__ C,
                                                   const float* __restrict__ att_s,
                                                   const float* __restrict__ att_d,
                                                   float* __restrict__ al_s,
                                                   float* __restrict__ al_d,
                                                   int M) {
  constexpr bool F32A = (sizeof(AT) == 4);
  __shared__ ushort sA[32 * LDS_STRIDE];
  __shared__ ushort sB[128 * LDS_STRIDE];
  const int tid = threadIdx.x;
  const int w = tid >> 6, lane = tid & 63;
  const int q = lane >> 4, lm = lane & 15;
  const int m0 = blockIdx.x * 32;

  f32x4 acc[2][2];
  #pragma unroll
  for (int i = 0; i < 2; i++)
    #pragma unroll
    for (int j = 0; j < 2; j++) acc[i][j] = {0.f, 0.f, 0.f, 0.f};

  for (int k0 = 0; k0 < KK; k0 += 64) {
    __syncthreads();
    if constexpr (F32A) {
      #pragma unroll
      for (int p = 0; p < 2; ++p) {
        int idx = p * 256 + tid;
        int r = idx >> 4;
        int c = (idx & 15) << 2;
        int row = min(m0 + r, M - 1);
        float4 v = *(const float4*)((const float*)A + (size_t)row * KK + k0 + c);
        ushort4 u;
        u.x = f2bf(v.x); u.y = f2bf(v.y); u.z = f2bf(v.z); u.w = f2bf(v.w);
        *(ushort4*)&sA[r * LDS_STRIDE + c] = u;
      }
    } else {
      int r = tid >> 3;
      int c = (tid & 7) << 3;
      int row = min(m0 + r, M - 1);
      *(bf16x8*)&sA[r * LDS_STRIDE + c] =
          *(const bf16x8*)((const ushort*)A + (size_t)row * KK + k0 + c);
    }
    #pragma unroll
    for (int p = 0; p < 4; ++p) {
      int idx = p * 256 + tid;
      int r = idx >> 3;
      int c = (idx & 7) << 3;
      *(bf16x8*)&sB[r * LDS_STRIDE + c] = *(const bf16x8*)(Bt + (size_t)r * KK + k0 + c);
    }
    __syncthreads();
    #pragma unroll
    for (int ks = 0; ks < 2; ++ks) {
      bf16x8 af[2], bfv[2];
      #pragma unroll
      for (int i = 0; i < 2; ++i)
        af[i] = *(const bf16x8*)&sA[(i * 16 + lm) * LDS_STRIDE + ks * 32 + q * 8];
      #pragma unroll
      for (int j = 0; j < 2; ++j)
        bfv[j] = *(const bf16x8*)&sB[(w * 32 + j * 16 + lm) * LDS_STRIDE + ks * 32 + q * 8];
      #pragma unroll
      for (int i = 0; i < 2; ++i)
        #pragma unroll
        for (int j = 0; j < 2; ++j)
          acc[i][j] = __builtin_amdgcn_mfma_f32_16x16x32_bf16(af[i], bfv[j], acc[i][j], 0, 0, 0);
    }
  }

  // epilogue: C/D layout col=lane&15, row=(lane>>4)*4+reg  [m89-verified]
  float asw[2], adw[2];
  if constexpr (ATT) {
    #pragma unroll
    for (int j = 0; j < 2; ++j) {
      asw[j] = att_s[(w * 2 + j) * 16 + lm];
      adw[j] = att_d[(w * 2 + j) * 16 + lm];
    }
  }
  #pragma unroll
  for (int i = 0; i < 2; ++i) {
    #pragma unroll
    for (int r = 0; r < 4; ++r) {
      int row = m0 + i * 16 + q * 4 + r;
      if (row < M) {
        #pragma unroll
        for (int j = 0; j < 2; ++j) {
          int colc = w * 32 + j * 16 + lm;
          float v = acc[i][j][r];
          if (RELU_BIAS) { v += bias[colc]; v = fmaxf(v, 0.f); }
          C[(size_t)row * 128 + colc] = f2bf(v);
        }
      }
    }
  }
  if constexpr (ATT) {
    #pragma unroll
    for (int i = 0; i < 2; ++i) {
      #pragma unroll
      for (int j = 0; j < 2; ++j) {
        #pragma unroll
        for (int r = 0; r < 4; ++r) {
          float ss = acc[i][j][r] * asw[j];
          float dd = acc[i][j][r] * adw[j];
          #pragma unroll
          for (int off = 1; off < 16; off <<= 1) {
            ss += __shfl_xor(ss, off);
            dd += __shfl_xor(dd, off);
          }
          if (lm == 0) {
            int row = m0 + i * 16 + q * 4 + r;
            if (row < M) {
              al_s[row * 8 + w * 2 + j] = ss;
              al_d[row * 8 + w * 2 + j] = dd;
            }
          }
        }
      }
    }
  }
}

// ---------------- GAT aggregation: SHUFFLE-FREE lane-local online softmax --------
// Key observation: the 8 source indices per chunk are WAVE-UNIFORM (col[start+c+j],
// one 32B line). Each lane loads them directly (broadcast loads), computes its own
// head's 8 logits from al_s[sj*8+head] (one 32B line per j), and runs the entire
// online softmax lane-locally — ZERO cross-lane ops in the loop (was ~20
// ds_bpermute/chunk on the LDS pipe, serializing against the gathers). 8-way logit
// redundancy across lanes of the same head is free at ~5% VALUBusy. Hot path
// (nv==8) is branch-free; tail chunks take a wave-uniform-predicated path
// (R1 lesson). pj = exp(-inf - m) = 0 keeps the shared accumulate unpredicated.
// Lane mapping: channels (2*lane, 2*lane+1), head = lane>>3 (= channel/16).
__global__ __launch_bounds__(256) void gat_aggregate(
    const ushort* __restrict__ xh, const float* __restrict__ al_s,
    const float* __restrict__ al_d, const int* __restrict__ rowptr,
    const int* __restrict__ col, const ushort* __restrict__ h_res,
    const float* __restrict__ gb, const float* __restrict__ lng,
    const float* __restrict__ lnb, ushort* __restrict__ h_out, int n) {
  const int lane = threadIdx.x & 63;
  const int node = (blockIdx.x * blockDim.x + threadIdx.x) >> 6;
  if (node >= n) return;
  const int head = lane >> 3;
  const unsigned* xw_base = (const unsigned*)xh;

  const int2 rp = *(const int2*)&rowptr[node];
  const int start = rp.x, end = rp.y;
  const int T = end - start + 1;              // + self-loop (item T-1)
  const float ald_c = al_d[node * 8 + head];

  float m = -INFINITY, denom = 0.f, acc0 = 0.f, acc1 = 0.f;

  for (int c = 0; c < T; c += 8) {
    int nv = T - c; if (nv > 8) nv = 8;       // wave-uniform
    int sj[8];
    float ej[8];
    unsigned xg[8];
    if (nv == 8) {
      // hot path: all loads unpredicated; col line -> gathers + logit lines
      #pragma unroll
      for (int j = 0; j < 8; ++j) {
        int idx = start + c + j;
        sj[j] = (idx < end) ? col[idx] : node;
      }
      #pragma unroll
      for (int j = 0; j < 8; ++j)
        xg[j] = xw_base[(size_t)sj[j] * 64 + lane];
      #pragma unroll
      for (int j = 0; j < 8; ++j) {
        float e = al_s[sj[j] * 8 + head] + ald_c;
        ej[j] = (e > 0.f) ? e : 0.2f * e;
      }
    } else {
      // tail: wave-uniform per-j predicates; skipped j contribute pj = 0
      #pragma unroll
      for (int j = 0; j < 8; ++j) {
        if (j < nv) {
          int idx = start + c + j;
          int s = (idx < end) ? col[idx] : node;
          xg[j] = xw_base[(size_t)s * 64 + lane];
          float e = al_s[s * 8 + head] + ald_c;
          ej[j] = (e > 0.f) ? e : 0.2f * e;
        } else {
          xg[j] = 0u;
          ej[j] = -INFINITY;
        }
      }
    }
    // lane-local online softmax (no cross-lane ops)
    float cm = ej[0];
    #pragma unroll
    for (int j = 1; j < 8; ++j) cm = fmaxf(cm, ej[j]);
    float newm = fmaxf(m, cm);
    float scale = __expf(m - newm);
    m = newm;
    denom *= scale; acc0 *= scale; acc1 *= scale;
    #pragma unroll
    for (int j = 0; j < 8; ++j) {
      float pj = __expf(ej[j] - m);
      denom += pj;
      acc0 = fmaf(pj, bflo(xg[j]), acc0);
      acc1 = fmaf(pj, bfhi(xg[j]), acc1);
    }
  }

  float inv = 1.f / denom;
  int c0 = lane * 2, c1 = c0 + 1;
  unsigned ur = ((const unsigned*)h_res)[(size_t)node * 64 + lane];
  float v0 = acc0 * inv + gb[c0] + bflo(ur);
  float v1 = acc1 * inv + gb[c1] + bfhi(ur);
  float sum = v0 + v1;
  #pragma unroll
  for (int off = 32; off; off >>= 1) sum += __shfl_xor(sum, off);
  float mean = sum * (1.f / 128.f);
  float d0 = v0 - mean, d1 = v1 - mean;
  float sq = d0 * d0 + d1 * d1;
  #pragma unroll
  for (int off = 32; off; off >>= 1) sq += __shfl_xor(sq, off);
  float rstd = rsqrtf(sq * (1.f / 128.f) + 1e-5f);
  float o0 = fmaxf(d0 * rstd * lng[c0] + lnb[c0], 0.f);
  float o1 = fmaxf(d1 * rstd * lng[c1] + lnb[c1], 0.f);
  ((unsigned*)h_out)[(size_t)node * 64 + lane] =
      (unsigned)f2bf(o0) | ((unsigned)f2bf(o1) << 16);
}

// ---------------- MFMA classifier (bf16 h in) ----------------
#define CSTR 136
#define HSTR 72
__global__ __launch_bounds__(256) void classifier_mfma(
    const ushort* __restrict__ h, const ushort* __restrict__ w1t,
    const float* __restrict__ b1, const ushort* __restrict__ w2t,
    const float* __restrict__ b2, float* __restrict__ out, int n) {
  __shared__ ushort sA[128 * CSTR];
  __shared__ ushort sB[64 * CSTR];
  __shared__ ushort sHid[128 * HSTR];
  const int tid = threadIdx.x;
  const int wave = tid >> 6, lane = tid & 63;
  const int q = lane >> 4, lm = lane & 15;
  const int wr = wave >> 1, wc = wave & 1;
  const int m0 = blockIdx.x * 128;

  #pragma unroll
  for (int p = 0; p < 8; ++p) {
    int idx = p * 256 + tid;
    int r = idx >> 4;
    int c = (idx & 15) << 3;
    int row = min(m0 + r, n - 1);
    *(bf16x8*)&sA[r * CSTR + c] = *(const bf16x8*)(h + (size_t)row * 128 + c);
  }
  #pragma unroll
  for (int p = 0; p < 4; ++p) {
    int idx = p * 256 + tid;
    int r = idx >> 4;
    int c = (idx & 15) << 3;
    *(bf16x8*)&sB[r * CSTR + c] = *(const bf16x8*)(w1t + r * 128 + c);
  }
  __syncthreads();

  f32x4 acc[4][2];
  #pragma unroll
  for (int i = 0; i < 4; ++i)
    #pragma unroll
    for (int j = 0; j < 2; ++j) acc[i][j] = {0.f, 0.f, 0.f, 0.f};
  #pragma unroll
  for (int ks = 0; ks < 4; ++ks) {
    bf16x8 af[4], bfv[2];
    #pragma unroll
    for (int t = 0; t < 4; ++t)
      af[t] = *(const bf16x8*)&sA[(wr * 64 + t * 16 + lm) * CSTR + ks * 32 + q * 8];
    #pragma unroll
    for (int j = 0; j < 2; ++j)
      bfv[j] = *(const bf16x8*)&sB[(wc * 32 + j * 16 + lm) * CSTR + ks * 32 + q * 8];
    #pragma unroll
    for (int i = 0; i < 4; ++i)
      #pragma unroll
      for (int j = 0; j < 2; ++j)
        acc[i][j] = __builtin_amdgcn_mfma_f32_16x16x32_bf16(af[i], bfv[j], acc[i][j], 0, 0, 0);
  }
  #pragma unroll
  for (int i = 0; i < 4; ++i) {
    #pragma unroll
    for (int j = 0; j < 2; ++j) {
      int colc = wc * 32 + j * 16 + lm;
      float bb = b1[colc];
      #pragma unroll
      for (int r = 0; r < 4; ++r) {
        int row = wr * 64 + i * 16 + q * 4 + r;
        float v = fmaxf(acc[i][j][r] + bb, 0.f);
        sHid[row * HSTR + colc] = f2bf(v);
      }
    }
  }
  __syncthreads();

  f32x4 acc2[2] = {{0.f, 0.f, 0.f, 0.f}, {0.f, 0.f, 0.f, 0.f}};
  #pragma unroll
  for (int ks = 0; ks < 2; ++ks) {
    bf16x8 b2f = *(const bf16x8*)(w2t + lm * 64 + ks * 32 + q * 8);
    #pragma unroll
    for (int t = 0; t < 2; ++t) {
      bf16x8 a2 = *(const bf16x8*)&sHid[(wave * 32 + t * 16 + lm) * HSTR + ks * 32 + q * 8];
      acc2[t] = __builtin_amdgcn_mfma_f32_16x16x32_bf16(a2, b2f, acc2[t], 0, 0, 0);
    }
  }
  float bb2 = b2[lm];
  #pragma unroll
  for (int t = 0; t < 2; ++t) {
    #pragma unroll
    for (int r = 0; r < 4; ++r) {
      int row = m0 + wave * 32 + t * 16 + q * 4 + r;
      float lg = acc2[t][r] + bb2;
      float mx = lg;
      #pragma unroll
      for (int off = 8; off; off >>= 1) mx = fmaxf(mx, __shfl_xor(mx, off, 16));
      float se = __expf(lg - mx);
      #pragma unroll
      for (int off = 8; off; off >>= 1) se += __shfl_xor(se, off, 16);
      if (row < n) out[(size_t)row * 16 + lm] = lg - mx - __logf(se);
    }
  }
}

// ---------------- launch ----------------
extern "C" void kernel_launch(void* const* d_in, const int* in_sizes, int n_in,
                              void* d_out, int out_size, void* d_ws, size_t ws_size,
                              hipStream_t stream) {
  const float* x       = (const float*)d_in[0];
  const int*   ei      = (const int*)d_in[1];
  const float* proj_w  = (const float*)d_in[2];
  const float* proj_b  = (const float*)d_in[3];
  const float* lin_w   = (const float*)d_in[4];
  const float* att_src = (const float*)d_in[5];
  const float* att_dst = (const float*)d_in[6];
  const float* gat_b   = (const float*)d_in[7];
  const float* ln_g    = (const float*)d_in[8];
  const float* ln_b    = (const float*)d_in[9];
  const float* cls_w1  = (const float*)d_in[10];
  const float* cls_b1  = (const float*)d_in[11];
  const float* cls_w2  = (const float*)d_in[12];
  const float* cls_b2  = (const float*)d_in[13];
  float* outp = (float*)d_out;

  const int N = NN, E = EE;
  ushort* wt   = (ushort*)d_ws;                     // 107520 used, reserve 108544
  ushort* h0   = wt + 108544;                       // N*128 bf16
  ushort* h1   = h0 + (size_t)N * 128;
  ushort* xh_u = h1 + (size_t)N * 128;
  float* als   = (float*)(xh_u + (size_t)N * 128);
  float* ald   = als + (size_t)N * NHEAD;
  int* counts  = (int*)(ald + (size_t)N * NHEAD);
  int* rowptr  = counts + N;
  int* woff    = rowptr + N + 1;
  int* col     = woff + N;
  int* agg     = col + E;                           // 196 lookback aggregates

  const int* e_src = ei;
  const int* e_dst = ei + E;

  init_kernel<<<SCAN_NBLK, 256, 0, stream>>>(counts, agg, N);
  prep_hist<<<HBLK + PBLK, 256, 0, stream>>>(
      proj_w, lin_w, cls_w1, cls_w2, wt, e_dst, counts);
  scan_lookback<<<SCAN_NBLK, 256, 0, stream>>>(counts, agg, rowptr, woff, N);
  scatter_proj<<<SBLK + GBLK, 256, 0, stream>>>(
      e_src, e_dst, woff, col, x, wt, proj_b, h0, N);

  ushort* hc = h0;
  ushort* hn = h1;
  for (int l = 0; l < 3; ++l) {
    mfma_gemm32<ushort, HIDD, false, true><<<GBLK, 256, 0, stream>>>(
        hc, wt + 49152 + l * 16384, nullptr, xh_u,
        att_src + l * 128, att_dst + l * 128, als, ald, N);
    gat_aggregate<<<(N + 3) / 4, 256, 0, stream>>>(
        xh_u, als, ald, rowptr, col, hc, gat_b + l * 128, ln_g + l * 128,
        ln_b + l * 128, hn, N);
    ushort* t = hc; hc = hn; hn = t;
  }
  classifier_mfma<<<(N + 127) / 128, 256, 0, stream>>>(
      hc, wt + 98304, cls_b1, wt + 106496, cls_b2, outp, N);
}

// Round 14
// 365.819 us; speedup vs baseline: 1.0981x; 1.0981x over previous
//
#include <hip/hip_runtime.h>
#include <hip/hip_bf16.h>
#include <math.h>

#define NN 50000
#define EE 500000
#define DIN 384
#define HIDD 128
#define NHEAD 8
#define OUTD 16

typedef __attribute__((ext_vector_type(8))) __bf16 bf16x8;
typedef __attribute__((ext_vector_type(4))) float f32x4;

__device__ __forceinline__ ushort f2bf(float f) {
  union { float f; unsigned u; } v; v.f = f;
  unsigned r = v.u + 0x7fffu + ((v.u >> 16) & 1u);
  return (ushort)(r >> 16);
}
__device__ __forceinline__ float bflo(unsigned w) {
  union { unsigned u; float f; } v; v.u = w << 16; return v.f;
}
__device__ __forceinline__ float bfhi(unsigned w) {
  union { unsigned u; float f; } v; v.u = w & 0xffff0000u; return v.f;
}

// ---------------- CSR build ----------------
__global__ void hist_kernel(const int* __restrict__ dst, int* __restrict__ counts, int e) {
  int i = blockIdx.x * blockDim.x + threadIdx.x;
  if (i < e) atomicAdd(&counts[dst[i]], 1);
}

#define SCAN_BS 256
#define SCAN_NBLK ((NN + SCAN_BS - 1) / SCAN_BS)  // 196

__global__ __launch_bounds__(256) void partial_sums(const int* __restrict__ counts,
                                                    int* __restrict__ bsum, int n) {
  __shared__ int red[256];
  int i = blockIdx.x * 256 + threadIdx.x;
  red[threadIdx.x] = (i < n) ? counts[i] : 0;
  __syncthreads();
  #pragma unroll
  for (int off = 128; off; off >>= 1) {
    if (threadIdx.x < off) red[threadIdx.x] += red[threadIdx.x + off];
    __syncthreads();
  }
  if (threadIdx.x == 0) bsum[blockIdx.x] = red[0];
}

__global__ __launch_bounds__(256) void scan_bsums(const int* __restrict__ bsum,
                                                  int* __restrict__ boff, int nb) {
  __shared__ int buf[256];
  int t = threadIdx.x;
  int v = (t < nb) ? bsum[t] : 0;
  buf[t] = v;
  __syncthreads();
  #pragma unroll
  for (int off = 1; off < 256; off <<= 1) {
    int u = (t >= off) ? buf[t - off] : 0;
    __syncthreads();
    buf[t] += u;
    __syncthreads();
  }
  if (t < nb) boff[t] = buf[t] - v;
}

__global__ __launch_bounds__(256) void final_scan(const int* __restrict__ counts,
                                                  const int* __restrict__ boff,
                                                  int* __restrict__ rowptr,
                                                  int* __restrict__ woff, int n) {
  __shared__ int buf[256];
  int i = blockIdx.x * 256 + threadIdx.x;
  int t = threadIdx.x;
  int v = (i < n) ? counts[i] : 0;
  buf[t] = v;
  __syncthreads();
  #pragma unroll
  for (int off = 1; off < 256; off <<= 1) {
    int u = (t >= off) ? buf[t - off] : 0;
    __syncthreads();
    buf[t] += u;
    __syncthreads();
  }
  int excl = boff[blockIdx.x] + buf[t] - v;
  if (i < n) { rowptr[i] = excl; woff[i] = excl; }
  if (i == n - 1) rowptr[n] = excl + v;
}

// ---------------- weight prep (+ counts zeroing folded in: spare threads) --------
// wt layout (ushort):
//  [0..49151]          proj_wt [n=128][k=384]
//  [49152 + l*16384]   lin_wt_l [n=128][k=128]   (l=0..2)
//  [98304..106495]     cls_w1t [n=64][k=128]
//  [106496..107519]    cls_w2t [n=16][k=64]
__global__ void prep_weights(const float* __restrict__ proj_w,
                             const float* __restrict__ lin_w,
                             const float* __restrict__ cls_w1,
                             const float* __restrict__ cls_w2,
                             ushort* __restrict__ wt,
                             int* __restrict__ counts) {
  int i = blockIdx.x * blockDim.x + threadIdx.x;
  if (i < NN) counts[i] = 0;
  if (i < 49152) {
    int k = i >> 7, n = i & 127;
    wt[n * 384 + k] = f2bf(proj_w[i]);
  } else if (i < 98304) {
    int j = i - 49152;
    int l = j >> 14, rem = j & 16383;
    int k = rem >> 7, n = rem & 127;
    wt[49152 + l * 16384 + n * 128 + k] = f2bf(lin_w[j]);
  } else if (i < 106496) {
    int j = i - 98304;
    int n = j >> 7, k = j & 127;
    wt[98304 + n * 128 + k] = f2bf(cls_w1[k * 64 + n]);
  } else if (i < 107520) {
    int j = i - 106496;
    int n = j >> 6, k = j & 63;
    wt[106496 + n * 64 + k] = f2bf(cls_w2[k * 16 + n]);
  }
}

#define LDS_STRIDE 68
#define SBLK ((EE + 255) / 256)   // 1954 scatter blocks
#define GBLK ((NN + 31) / 32)     // 1563 GEMM blocks

// ---------------- fused scatter + proj GEMM (R10 verified best: 366.3us) ---------
// Blocks [0, SBLK): CSR scatter (short, atomic-bound, returns before any barrier —
// block-uniform branch so no divergent-barrier hazard). Blocks [SBLK, SBLK+GBLK):
// proj GEMM C[N,128] = relu(x @ proj_wt + b), 32-row M-tile. Scatter-first mapping
// (R12's interleaved variant regressed: GEMM locality loss > overlap gain).
__global__ __launch_bounds__(256) void scatter_proj(
    const int* __restrict__ src, const int* __restrict__ dst,
    int* __restrict__ woff, int* __restrict__ col,
    const float* __restrict__ A, const ushort* __restrict__ Bt,
    const float* __restrict__ bias, ushort* __restrict__ C, int M) {
  __shared__ ushort sA[32 * LDS_STRIDE];
  __shared__ ushort sB[128 * LDS_STRIDE];
  const int bx = blockIdx.x;
  if (bx < SBLK) {
    int i = bx * 256 + threadIdx.x;
    if (i < EE) {
      int p = atomicAdd(&woff[dst[i]], 1);
      col[p] = src[i];
    }
    return;
  }
  const int tid = threadIdx.x;
  const int w = tid >> 6, lane = tid & 63;
  const int q = lane >> 4, lm = lane & 15;
  const int m0 = (bx - SBLK) * 32;

  f32x4 acc[2][2];
  #pragma unroll
  for (int i = 0; i < 2; i++)
    #pragma unroll
    for (int j = 0; j < 2; j++) acc[i][j] = {0.f, 0.f, 0.f, 0.f};

  for (int k0 = 0; k0 < DIN; k0 += 64) {
    __syncthreads();
    #pragma unroll
    for (int p = 0; p < 2; ++p) {
      int idx = p * 256 + tid;
      int r = idx >> 4;
      int c = (idx & 15) << 2;
      int row = min(m0 + r, M - 1);
      float4 v = *(const float4*)(A + (size_t)row * DIN + k0 + c);
      ushort4 u;
      u.x = f2bf(v.x); u.y = f2bf(v.y); u.z = f2bf(v.z); u.w = f2bf(v.w);
      *(ushort4*)&sA[r * LDS_STRIDE + c] = u;
    }
    #pragma unroll
    for (int p = 0; p < 4; ++p) {
      int idx = p * 256 + tid;
      int r = idx >> 3;
      int c = (idx & 7) << 3;
      *(bf16x8*)&sB[r * LDS_STRIDE + c] = *(const bf16x8*)(Bt + (size_t)r * DIN + k0 + c);
    }
    __syncthreads();
    #pragma unroll
    for (int ks = 0; ks < 2; ++ks) {
      bf16x8 af[2], bfv[2];
      #pragma unroll
      for (int i = 0; i < 2; ++i)
        af[i] = *(const bf16x8*)&sA[(i * 16 + lm) * LDS_STRIDE + ks * 32 + q * 8];
      #pragma unroll
      for (int j = 0; j < 2; ++j)
        bfv[j] = *(const bf16x8*)&sB[(w * 32 + j * 16 + lm) * LDS_STRIDE + ks * 32 + q * 8];
      #pragma unroll
      for (int i = 0; i < 2; ++i)
        #pragma unroll
        for (int j = 0; j < 2; ++j)
          acc[i][j] = __builtin_amdgcn_mfma_f32_16x16x32_bf16(af[i], bfv[j], acc[i][j], 0, 0, 0);
    }
  }
  #pragma unroll
  for (int i = 0; i < 2; ++i) {
    #pragma unroll
    for (int r = 0; r < 4; ++r) {
      int row = m0 + i * 16 + q * 4 + r;
      if (row < M) {
        #pragma unroll
        for (int j = 0; j < 2; ++j) {
          int colc = w * 32 + j * 16 + lm;
          float v = acc[i][j][r] + bias[colc];
          C[(size_t)row * 128 + colc] = f2bf(fmaxf(v, 0.f));
        }
      }
    }
  }
}

// ---------------- MFMA GEMM: C[M,128] = A[M,128] @ B[128,128], bf16 out ----------
// 32-row M-tile (1563 blocks, 7 blocks/CU at 21.75 KB LDS — R5/R6 verified TLP win).
// ATT: fused attention logits; head = wave*2 + j, chan = lm (16-lane shfl reduce).
template<typename AT, int KK, bool RELU_BIAS, bool ATT>
__global__ __launch_bounds__(256) void mfma_gemm32(const AT* __restrict__ A,
                                                   const ushort* __restrict__ Bt,
                                                   const float* __restrict__ bias,
                                                   ushort* __restrict__ C,
                                                   const float* __restrict__ att_s,
                                                   const float* __restrict__ att_d,
                                                   float* __restrict__ al_s,
                                                   float* __restrict__ al_d,
                                                   int M) {
  constexpr bool F32A = (sizeof(AT) == 4);
  __shared__ ushort sA[32 * LDS_STRIDE];
  __shared__ ushort sB[128 * LDS_STRIDE];
  const int tid = threadIdx.x;
  const int w = tid >> 6, lane = tid & 63;
  const int q = lane >> 4, lm = lane & 15;
  const int m0 = blockIdx.x * 32;

  f32x4 acc[2][2];
  #pragma unroll
  for (int i = 0; i < 2; i++)
    #pragma unroll
    for (int j = 0; j < 2; j++) acc[i][j] = {0.f, 0.f, 0.f, 0.f};

  for (int k0 = 0; k0 < KK; k0 += 64) {
    __syncthreads();
    if constexpr (F32A) {
      #pragma unroll
      for (int p = 0; p < 2; ++p) {
        int idx = p * 256 + tid;
        int r = idx >> 4;
        int c = (idx & 15) << 2;
        int row = min(m0 + r, M - 1);
        float4 v = *(const float4*)((const float*)A + (size_t)row * KK + k0 + c);
        ushort4 u;
        u.x = f2bf(v.x); u.y = f2bf(v.y); u.z = f2bf(v.z); u.w = f2bf(v.w);
        *(ushort4*)&sA[r * LDS_STRIDE + c] = u;
      }
    } else {
      int r = tid >> 3;
      int c = (tid & 7) << 3;
      int row = min(m0 + r, M - 1);
      *(bf16x8*)&sA[r * LDS_STRIDE + c] =
          *(const bf16x8*)((const ushort*)A + (size_t)row * KK + k0 + c);
    }
    #pragma unroll
    for (int p = 0; p < 4; ++p) {
      int idx = p * 256 + tid;
      int r = idx >> 3;
      int c = (idx & 7) << 3;
      *(bf16x8*)&sB[r * LDS_STRIDE + c] = *(const bf16x8*)(Bt + (size_t)r * KK + k0 + c);
    }
    __syncthreads();
    #pragma unroll
    for (int ks = 0; ks < 2; ++ks) {
      bf16x8 af[2], bfv[2];
      #pragma unroll
      for (int i = 0; i < 2; ++i)
        af[i] = *(const bf16x8*)&sA[(i * 16 + lm) * LDS_STRIDE + ks * 32 + q * 8];
      #pragma unroll
      for (int j = 0; j < 2; ++j)
        bfv[j] = *(const bf16x8*)&sB[(w * 32 + j * 16 + lm) * LDS_STRIDE + ks * 32 + q * 8];
      #pragma unroll
      for (int i = 0; i < 2; ++i)
        #pragma unroll
        for (int j = 0; j < 2; ++j)
          acc[i][j] = __builtin_amdgcn_mfma_f32_16x16x32_bf16(af[i], bfv[j], acc[i][j], 0, 0, 0);
    }
  }

  // epilogue: C/D layout col=lane&15, row=(lane>>4)*4+reg  [m89-verified]
  float asw[2], adw[2];
  if constexpr (ATT) {
    #pragma unroll
    for (int j = 0; j < 2; ++j) {
      asw[j] = att_s[(w * 2 + j) * 16 + lm];
      adw[j] = att_d[(w * 2 + j) * 16 + lm];
    }
  }
  #pragma unroll
  for (int i = 0; i < 2; ++i) {
    #pragma unroll
    for (int r = 0; r < 4; ++r) {
      int row = m0 + i * 16 + q * 4 + r;
      if (row < M) {
        #pragma unroll
        for (int j = 0; j < 2; ++j) {
          int colc = w * 32 + j * 16 + lm;
          float v = acc[i][j][r];
          if (RELU_BIAS) { v += bias[colc]; v = fmaxf(v, 0.f); }
          C[(size_t)row * 128 + colc] = f2bf(v);
        }
      }
    }
  }
  if constexpr (ATT) {
    #pragma unroll
    for (int i = 0; i < 2; ++i) {
      #pragma unroll
      for (int j = 0; j < 2; ++j) {
        #pragma unroll
        for (int r = 0; r < 4; ++r) {
          float ss = acc[i][j][r] * asw[j];
          float dd = acc[i][j][r] * adw[j];
          #pragma unroll
          for (int off = 1; off < 16; off <<= 1) {
            ss += __shfl_xor(ss, off);
            dd += __shfl_xor(dd, off);
          }
          if (lm == 0) {
            int row = m0 + i * 16 + q * 4 + r;
            if (row < M) {
              al_s[row * 8 + w * 2 + j] = ss;
              al_d[row * 8 + w * 2 + j] = dd;
            }
          }
        }
      }
    }
  }
}

// ---------------- GAT aggregation: 8-edge-parallel chunk-online softmax ----------
// R6 verbatim (verified best): int2 rowptr + col-only s_pf prefetch whose first use
// is deferred one iteration. Refuted alternatives: deep gather pipeline (R8: rotation
// overhead), same-iteration als prefetch (R9: pulls col latency onto critical path),
// shuffle-free lane-local (R13: 8x VMEM instruction explosion — shuffles amortize
// one coalesced load across 8 consumers; LDS pipe was never the bottleneck).
__global__ __launch_bounds__(256) void gat_aggregate(
    const ushort* __restrict__ xh, const float* __restrict__ al_s,
    const float* __restrict__ al_d, const int* __restrict__ rowptr,
    const int* __restrict__ col, const ushort* __restrict__ h_res,
    const float* __restrict__ gb, const float* __restrict__ lng,
    const float* __restrict__ lnb, ushort* __restrict__ h_out, int n) {
  const int lane = threadIdx.x & 63;
  const int node = (blockIdx.x * blockDim.x + threadIdx.x) >> 6;
  if (node >= n) return;
  const int e8 = lane >> 3;     // compute mapping: edge-in-chunk
  const int hh = lane & 7;      // compute mapping: head
  const int head = lane >> 3;   // accumulate mapping: head
  const unsigned* xw_base = (const unsigned*)xh;

  const int2 rp = *(const int2*)&rowptr[node];
  const int start = rp.x, end = rp.y;
  const int T = end - start + 1;              // + self-loop (item T-1)
  const float ald_c = al_d[node * 8 + hh];

  float m = -INFINITY, denom = 0.f, acc0 = 0.f, acc1 = 0.f;

  // prefetch chunk 0's source index
  int idx0 = start + e8;
  int s_pf = (e8 < T && idx0 < end) ? col[idx0] : node;

  for (int c = 0; c < T; c += 8) {
    int it = c + e8;
    bool valid = it < T;
    int s = s_pf;
    // prefetch next chunk's col (wave-uniform branch; first use deferred one iter)
    if (c + 8 < T) {
      int itn = c + 8 + e8;
      int idxn = start + itn;
      s_pf = (itn < T && idxn < end) ? col[idxn] : node;
    }
    float e = al_s[s * 8 + hh] + ald_c;
    e = (e > 0.f) ? e : 0.2f * e;
    if (!valid) e = -INFINITY;
    float cm = e;
    cm = fmaxf(cm, __shfl_xor(cm, 8));
    cm = fmaxf(cm, __shfl_xor(cm, 16));
    cm = fmaxf(cm, __shfl_xor(cm, 32));
    float newm = fmaxf(m, __shfl(cm, head));
    float newm_c = __shfl(newm, hh * 8);
    float p_lane = __expf(e - newm_c);
    float scale = __expf(m - newm);
    m = newm;
    unsigned xg[8];
    int sj[8];
    #pragma unroll
    for (int j = 0; j < 8; ++j) sj[j] = __shfl(s, j * 8);
    #pragma unroll
    for (int j = 0; j < 8; ++j) xg[j] = xw_base[(size_t)sj[j] * 64 + lane];
    denom *= scale; acc0 *= scale; acc1 *= scale;
    #pragma unroll
    for (int j = 0; j < 8; ++j) {
      float pj = __shfl(p_lane, j * 8 + head);
      denom += pj;
      acc0 = fmaf(pj, bflo(xg[j]), acc0);
      acc1 = fmaf(pj, bfhi(xg[j]), acc1);
    }
  }

  float inv = 1.f / denom;
  int c0 = lane * 2, c1 = c0 + 1;
  unsigned ur = ((const unsigned*)h_res)[(size_t)node * 64 + lane];
  float v0 = acc0 * inv + gb[c0] + bflo(ur);
  float v1 = acc1 * inv + gb[c1] + bfhi(ur);
  float sum = v0 + v1;
  #pragma unroll
  for (int off = 32; off; off >>= 1) sum += __shfl_xor(sum, off);
  float mean = sum * (1.f / 128.f);
  float d0 = v0 - mean, d1 = v1 - mean;
  float sq = d0 * d0 + d1 * d1;
  #pragma unroll
  for (int off = 32; off; off >>= 1) sq += __shfl_xor(sq, off);
  float rstd = rsqrtf(sq * (1.f / 128.f) + 1e-5f);
  float o0 = fmaxf(d0 * rstd * lng[c0] + lnb[c0], 0.f);
  float o1 = fmaxf(d1 * rstd * lng[c1] + lnb[c1], 0.f);
  ((unsigned*)h_out)[(size_t)node * 64 + lane] =
      (unsigned)f2bf(o0) | ((unsigned)f2bf(o1) << 16);
}

// ---------------- MFMA classifier (bf16 h in) ----------------
#define CSTR 136
#define HSTR 72
__global__ __launch_bounds__(256) void classifier_mfma(
    const ushort* __restrict__ h, const ushort* __restrict__ w1t,
    const float* __restrict__ b1, const ushort* __restrict__ w2t,
    const float* __restrict__ b2, float* __restrict__ out, int n) {
  __shared__ ushort sA[128 * CSTR];
  __shared__ ushort sB[64 * CSTR];
  __shared__ ushort sHid[128 * HSTR];
  const int tid = threadIdx.x;
  const int wave = tid >> 6, lane = tid & 63;
  const int q = lane >> 4, lm = lane & 15;
  const int wr = wave >> 1, wc = wave & 1;
  const int m0 = blockIdx.x * 128;

  #pragma unroll
  for (int p = 0; p < 8; ++p) {
    int idx = p * 256 + tid;
    int r = idx >> 4;
    int c = (idx & 15) << 3;
    int row = min(m0 + r, n - 1);
    *(bf16x8*)&sA[r * CSTR + c] = *(const bf16x8*)(h + (size_t)row * 128 + c);
  }
  #pragma unroll
  for (int p = 0; p < 4; ++p) {
    int idx = p * 256 + tid;
    int r = idx >> 4;
    int c = (idx & 15) << 3;
    *(bf16x8*)&sB[r * CSTR + c] = *(const bf16x8*)(w1t + r * 128 + c);
  }
  __syncthreads();

  f32x4 acc[4][2];
  #pragma unroll
  for (int i = 0; i < 4; ++i)
    #pragma unroll
    for (int j = 0; j < 2; ++j) acc[i][j] = {0.f, 0.f, 0.f, 0.f};
  #pragma unroll
  for (int ks = 0; ks < 4; ++ks) {
    bf16x8 af[4], bfv[2];
    #pragma unroll
    for (int t = 0; t < 4; ++t)
      af[t] = *(const bf16x8*)&sA[(wr * 64 + t * 16 + lm) * CSTR + ks * 32 + q * 8];
    #pragma unroll
    for (int j = 0; j < 2; ++j)
      bfv[j] = *(const bf16x8*)&sB[(wc * 32 + j * 16 + lm) * CSTR + ks * 32 + q * 8];
    #pragma unroll
    for (int i = 0; i < 4; ++i)
      #pragma unroll
      for (int j = 0; j < 2; ++j)
        acc[i][j] = __builtin_amdgcn_mfma_f32_16x16x32_bf16(af[i], bfv[j], acc[i][j], 0, 0, 0);
  }
  #pragma unroll
  for (int i = 0; i < 4; ++i) {
    #pragma unroll
    for (int j = 0; j < 2; ++j) {
      int colc = wc * 32 + j * 16 + lm;
      float bb = b1[colc];
      #pragma unroll
      for (int r = 0; r < 4; ++r) {
        int row = wr * 64 + i * 16 + q * 4 + r;
        float v = fmaxf(acc[i][j][r] + bb, 0.f);
        sHid[row * HSTR + colc] = f2bf(v);
      }
    }
  }
  __syncthreads();

  f32x4 acc2[2] = {{0.f, 0.f, 0.f, 0.f}, {0.f, 0.f, 0.f, 0.f}};
  #pragma unroll
  for (int ks = 0; ks < 2; ++ks) {
    bf16x8 b2f = *(const bf16x8*)(w2t + lm * 64 + ks * 32 + q * 8);
    #pragma unroll
    for (int t = 0; t < 2; ++t) {
      bf16x8 a2 = *(const bf16x8*)&sHid[(wave * 32 + t * 16 + lm) * HSTR + ks * 32 + q * 8];
      acc2[t] = __builtin_amdgcn_mfma_f32_16x16x32_bf16(a2, b2f, acc2[t], 0, 0, 0);
    }
  }
  float bb2 = b2[lm];
  #pragma unroll
  for (int t = 0; t < 2; ++t) {
    #pragma unroll
    for (int r = 0; r < 4; ++r) {
      int row = m0 + wave * 32 + t * 16 + q * 4 + r;
      float lg = acc2[t][r] + bb2;
      float mx = lg;
      #pragma unroll
      for (int off = 8; off; off >>= 1) mx = fmaxf(mx, __shfl_xor(mx, off, 16));
      float se = __expf(lg - mx);
      #pragma unroll
      for (int off = 8; off; off >>= 1) se += __shfl_xor(se, off, 16);
      if (row < n) out[(size_t)row * 16 + lm] = lg - mx - __logf(se);
    }
  }
}

// ---------------- launch ----------------
extern "C" void kernel_launch(void* const* d_in, const int* in_sizes, int n_in,
                              void* d_out, int out_size, void* d_ws, size_t ws_size,
                              hipStream_t stream) {
  const float* x       = (const float*)d_in[0];
  const int*   ei      = (const int*)d_in[1];
  const float* proj_w  = (const float*)d_in[2];
  const float* proj_b  = (const float*)d_in[3];
  const float* lin_w   = (const float*)d_in[4];
  const float* att_src = (const float*)d_in[5];
  const float* att_dst = (const float*)d_in[6];
  const float* gat_b   = (const float*)d_in[7];
  const float* ln_g    = (const float*)d_in[8];
  const float* ln_b    = (const float*)d_in[9];
  const float* cls_w1  = (const float*)d_in[10];
  const float* cls_b1  = (const float*)d_in[11];
  const float* cls_w2  = (const float*)d_in[12];
  const float* cls_b2  = (const float*)d_in[13];
  float* outp = (float*)d_out;

  const int N = NN, E = EE;
  ushort* wt   = (ushort*)d_ws;                     // 107520 used, reserve 108544
  ushort* h0   = wt + 108544;                       // N*128 bf16
  ushort* h1   = h0 + (size_t)N * 128;
  ushort* xh_u = h1 + (size_t)N * 128;
  float* als   = (float*)(xh_u + (size_t)N * 128);
  float* ald   = als + (size_t)N * NHEAD;
  int* counts  = (int*)(ald + (size_t)N * NHEAD);
  int* rowptr  = counts + N;
  int* woff    = rowptr + N + 1;
  int* col     = woff + N;
  int* bsum    = col + E;
  int* boff    = bsum + SCAN_NBLK;

  const int* e_src = ei;
  const int* e_dst = ei + E;

  prep_weights<<<(107520 + 255) / 256, 256, 0, stream>>>(
      proj_w, lin_w, cls_w1, cls_w2, wt, counts);

  hist_kernel<<<(E + 255) / 256, 256, 0, stream>>>(e_dst, counts, E);
  partial_sums<<<SCAN_NBLK, 256, 0, stream>>>(counts, bsum, N);
  scan_bsums<<<1, 256, 0, stream>>>(bsum, boff, SCAN_NBLK);
  final_scan<<<SCAN_NBLK, 256, 0, stream>>>(counts, boff, rowptr, woff, N);

  // scatter + proj GEMM fused into one dispatch (independent; scatter hides in GEMM)
  scatter_proj<<<SBLK + GBLK, 256, 0, stream>>>(
      e_src, e_dst, woff, col, x, wt, proj_b, h0, N);

  ushort* hc = h0;
  ushort* hn = h1;
  for (int l = 0; l < 3; ++l) {
    mfma_gemm32<ushort, HIDD, false, true><<<GBLK, 256, 0, stream>>>(
        hc, wt + 49152 + l * 16384, nullptr, xh_u,
        att_src + l * 128, att_dst + l * 128, als, ald, N);
    gat_aggregate<<<(N + 3) / 4, 256, 0, stream>>>(
        xh_u, als, ald, rowptr, col, hc, gat_b + l * 128, ln_g + l * 128,
        ln_b + l * 128, hn, N);
    ushort* t = hc; hc = hn; hn = t;
  }
  classifier_mfma<<<(N + 127) / 128, 256, 0, stream>>>(
      hc, wt + 98304, cls_b1, wt + 106496, cls_b2, outp, N);
}